// Round 1
// baseline (282.497 us; speedup 1.0000x reference)
//
#include <hip/hip_runtime.h>

// B=16, T=2048, C=200, H=64 attention head with padding mask.
// Round 7: attn occupancy 2->4 waves/SIMD. Previous grid (512 blocks x 4 waves) was
// grid-limited to 2 waves/SIMD (Occupancy 17%, MfmaUtil 14%, VALU 35%, HBM 13% -> latency
// bound). Now 8 waves/block (512 thr), key-split 256/wave, kt loop of 4; inner loop body
// unchanged. LDS 80KB -> exactly 2 blocks/CU; __launch_bounds__(512,4) caps VGPR at 128.
// 8-way split combined via LDS tree (4 barriers) instead of 8 sequential steps.

typedef __attribute__((ext_vector_type(8))) __bf16 bf16x8;
typedef __attribute__((ext_vector_type(4))) __bf16 bf16x4;
typedef __attribute__((ext_vector_type(4))) float f32x4;

#define T_SEQ 2048
#define C_DIM 200
#define H_DIM 64
#define BT_TOT 32768
#define QKV_ELEMS 2097152
#define PPAD 72            // P row pad (bf16): 2-way bank alias only
#define OPAD 68            // combine row pad (f32)
#define WTF_FULL 36864     // ks 0..5 full chunks: 6 * (3w*4t) * 512
#define WTF_ELEMS 38400    // + compact ks=6 chunk: 3*4*128 (c=192..199 only)
#define WTF_A_ELEMS 24576  // ks 0..3 (phase A, 48KB)
#define LOG2E 1.44269504088896f

// ---------------- Kernel 0: repack weights, compact MFMA fragment order ----------------
// Full chunk (ks<6, w, t): 512 bf16, elem lane*8+j = W_w[c=ks*32+(lane>>4)*8+j][h=t*16+(lane&15)]
// Compact ks=6 chunk (w, t): 128 bf16, elem l15*8+j = W_w[c=192+j][h=t*16+l15].
// w0 = Wq * (H^-0.5 * log2 e): scores land in log2 domain.
__global__ void prep_w(const float* __restrict__ Wk, const float* __restrict__ Wq,
                       const float* __restrict__ Wv, __bf16* __restrict__ WtF) {
    int idx = blockIdx.x * 256 + threadIdx.x;
    if (idx >= WTF_ELEMS) return;
    int w, c, h;
    if (idx < WTF_FULL) {
        int j = idx & 7, lane = (idx >> 3) & 63;
        int chunk = idx >> 9;                 // ks*12 + w*4 + t
        int t = chunk & 3, rest = chunk >> 2; // ks*3 + w
        w = rest % 3; int ks = rest / 3;
        c = ks * 32 + (lane >> 4) * 8 + j;
        h = t * 16 + (lane & 15);
    } else {
        int i2 = idx - WTF_FULL;
        int j = i2 & 7, l15 = (i2 >> 3) & 15, t = (i2 >> 7) & 3;
        w = i2 >> 9;
        c = 192 + j;
        h = t * 16 + l15;
    }
    const float* W = (w == 0) ? Wq : (w == 1) ? Wk : Wv;  // [C][H]
    float val = W[c * H_DIM + h];
    if (w == 0) val *= 0.125f * LOG2E;
    WtF[idx] = (__bf16)val;
}

// ---------------- Kernel 1: QKV projection ----------------
// grid = 512 blocks x 256 threads (4 waves x 16 rows = 64 rows/block), 2 waves/SIMD.
// W staged in LDS (two phases, 48KB); x direct-from-global A-fragments; vT via LDS transpose.
__global__ __launch_bounds__(256) void qkv_proj(const float* __restrict__ x,
                                                const __bf16* __restrict__ WtF,
                                                __bf16* __restrict__ qb,
                                                __bf16* __restrict__ kb,
                                                __bf16* __restrict__ vT) {
    __shared__ __bf16 Wl[WTF_A_ELEMS];  // 49152 B; reused phase B + transpose epilogue

    const int tid = threadIdx.x;
    const int wave = tid >> 6, lane = tid & 63, l15 = lane & 15, quad = lane >> 4;
    const int m0b = blockIdx.x * 64;
    const int row0 = m0b + wave * 16;

    f32x4 acc[3][4] = {};  // [w][h-tile], 16 rows per wave

    // ---- phase A: stage ks 0..3 (3072 x 16B over 256 threads = 12 iters), compute ----
    #pragma unroll
    for (int i = 0; i < 12; ++i) {
        const int c = i * 256 + tid;
        *(bf16x8*)(Wl + c * 8) = *(const bf16x8*)(WtF + c * 8);
    }
    __syncthreads();
    #pragma unroll
    for (int ks = 0; ks < 4; ++ks) {
        const float* xr = x + (size_t)(row0 + l15) * C_DIM + ks * 32 + quad * 8;
        const float4 f0 = *(const float4*)xr;
        const float4 f1 = *(const float4*)(xr + 4);
        bf16x8 a;
        a[0]=(__bf16)f0.x; a[1]=(__bf16)f0.y; a[2]=(__bf16)f0.z; a[3]=(__bf16)f0.w;
        a[4]=(__bf16)f1.x; a[5]=(__bf16)f1.y; a[6]=(__bf16)f1.z; a[7]=(__bf16)f1.w;
        #pragma unroll
        for (int w = 0; w < 3; ++w)
            #pragma unroll
            for (int t = 0; t < 4; ++t) {
                const bf16x8 bf = *(const bf16x8*)(Wl + ((ks * 12 + w * 4 + t) << 9) + lane * 8);
                acc[w][t] = __builtin_amdgcn_mfma_f32_16x16x32_bf16(a, bf, acc[w][t], 0, 0, 0);
            }
    }
    __syncthreads();

    // ---- phase B: stage ks 4..6 (1728 x 16B = 7 guarded iters), compute ----
    #pragma unroll
    for (int i = 0; i < 7; ++i) {
        const int c = i * 256 + tid;
        if (c < 1728)
            *(bf16x8*)(Wl + c * 8) = *(const bf16x8*)(WtF + WTF_A_ELEMS + c * 8);
    }
    __syncthreads();
    #pragma unroll
    for (int ks = 4; ks < 7; ++ks) {
        bf16x8 a;
        if (ks < 6 || quad == 0) {
            // ks=6,quad0 reads c 192..199 exactly (in-bounds); other quads are c>=200 -> A=0
            const float* xr = x + (size_t)(row0 + l15) * C_DIM + ks * 32 + quad * 8;
            const float4 f0 = *(const float4*)xr;
            const float4 f1 = *(const float4*)(xr + 4);
            a[0]=(__bf16)f0.x; a[1]=(__bf16)f0.y; a[2]=(__bf16)f0.z; a[3]=(__bf16)f0.w;
            a[4]=(__bf16)f1.x; a[5]=(__bf16)f1.y; a[6]=(__bf16)f1.z; a[7]=(__bf16)f1.w;
        } else {
            #pragma unroll
            for (int j = 0; j < 8; ++j) a[j] = (__bf16)0.f;
        }
        #pragma unroll
        for (int w = 0; w < 3; ++w)
            #pragma unroll
            for (int t = 0; t < 4; ++t) {
                // ks=6: compact chunk; quads 1..3 read quad0's data -> harmless (A rows are 0)
                const int off = (ks < 6) ? (((ks - 4) * 12 + w * 4 + t) << 9) + lane * 8
                                         : 12288 + ((w * 4 + t) << 7) + l15 * 8;
                const bf16x8 bf = *(const bf16x8*)(Wl + off);
                acc[w][t] = __builtin_amdgcn_mfma_f32_16x16x32_bf16(a, bf, acc[w][t], 0, 0, 0);
            }
    }

    // ---- epilogue: q,k direct stores; vT via LDS transpose for coalesced b128 ----
    #pragma unroll
    for (int t = 0; t < 4; ++t)
        #pragma unroll
        for (int r = 0; r < 4; ++r) {
            const size_t m = row0 + quad * 4 + r;
            qb[m * H_DIM + t * 16 + l15] = (__bf16)acc[0][t][r];
            kb[m * H_DIM + t * 16 + l15] = (__bf16)acc[1][t][r];
        }
    __syncthreads();
    #pragma unroll
    for (int t = 0; t < 4; ++t)
        #pragma unroll
        for (int r = 0; r < 4; ++r)
            Wl[(t * 16 + l15) * 72 + wave * 16 + quad * 4 + r] = (__bf16)acc[2][t][r];
    __syncthreads();
    const int bb = m0b >> 11, tloc = m0b & 2047;
    #pragma unroll
    for (int i = 0; i < 2; ++i) {
        const int seg = i * 256 + tid;          // 512 segs: h row, 8-elem column chunk
        const int h = seg >> 3, s8 = seg & 7;
        *(bf16x8*)(vT + ((size_t)bb * H_DIM + h) * T_SEQ + tloc + s8 * 8) =
            *(const bf16x8*)(Wl + h * 72 + s8 * 8);
    }
}

// ---------------- Kernel 2: attention, 64 queries/block, 8 key-splits, pipelined ----------------
// grid = (T/64, B); block = 512 (8 waves = 8 key-splits of 256, all same 64-q tile).
// 2 blocks/CU x 8 waves = 4 waves/SIMD. No-max softmax in log2 domain.
__global__ __launch_bounds__(512, 4) void attn(const __bf16* __restrict__ qb,
                                               const __bf16* __restrict__ kb,
                                               const __bf16* __restrict__ vT,
                                               const int* __restrict__ pm,
                                               float* __restrict__ out) {
    // arena: [0,8K) key bias f32[2048]; [8K,+73728) per-wave P (8 x 64 x PPAD bf16),
    // unioned with combine region: 4x Ocomb[64][OPAD] f32 + Lc[4][64] f32 (70656 B).
    __shared__ __align__(16) char arena[8192 + 8 * 64 * PPAD * 2];  // 81920 B
    float* biasS = (float*)arena;

    const int tid = threadIdx.x;
    const int wave = tid >> 6, lane = tid & 63, l15 = lane & 15, quad = lane >> 4;
    const int ks = wave;
    const int b = blockIdx.y;
    const int q0 = blockIdx.x * 64;
    const size_t bT = (size_t)b * T_SEQ;

    {
        const int4 p4 = *(const int4*)(pm + bT + tid * 4);
        biasS[tid * 4 + 0] = p4.x ? 0.f : -1e30f;
        biasS[tid * 4 + 1] = p4.y ? 0.f : -1e30f;
        biasS[tid * 4 + 2] = p4.z ? 0.f : -1e30f;
        biasS[tid * 4 + 3] = p4.w ? 0.f : -1e30f;
    }
    __syncthreads();

    // Q fragments: qa[mt][s], lane holds Q[q0+mt*16+l15][s*32+quad*8 ..+8]
    bf16x8 qa[4][2];
    #pragma unroll
    for (int mt = 0; mt < 4; ++mt)
        #pragma unroll
        for (int s = 0; s < 2; ++s)
            qa[mt][s] = *(const bf16x8*)(qb + (bT + q0 + mt * 16 + l15) * H_DIM + s * 32 + quad * 8);

    __bf16* P = (__bf16*)(arena + 8192) + wave * (64 * PPAD);
    const __bf16* kbase = kb + bT * H_DIM;
    const __bf16* vbase = vT + (size_t)b * H_DIM * T_SEQ;

    f32x4 oacc[4][4] = {};              // O'[qtile][h-tile][row=quad*4+r]
    float lsum[4] = {0.f, 0.f, 0.f, 0.f};

    // preload K fragments for tile 0: kf[n*2+s] = K[key0+n*16+l15][s*32+quad*8 ..+8]
    bf16x8 kf[8];
    #pragma unroll
    for (int n = 0; n < 4; ++n)
        #pragma unroll
        for (int s = 0; s < 2; ++s)
            kf[n * 2 + s] = *(const bf16x8*)(kbase + (ks * 256 + n * 16 + l15) * H_DIM + s * 32 + quad * 8);

    for (int kt = 0; kt < 4; ++kt) {
        const int key0 = ks * 256 + kt * 64;

        // issue V loads for THIS tile now (consumed after S+exp, ~700 cyc later)
        bf16x8 vf[8];
        #pragma unroll
        for (int t = 0; t < 4; ++t)
            #pragma unroll
            for (int s = 0; s < 2; ++s)
                vf[t * 2 + s] = *(const bf16x8*)(vbase + (size_t)(t * 16 + l15) * T_SEQ + key0 + s * 32 + quad * 8);

        // S'^T per n-block: 4 q-tiles share each K fragment; exp; P -> LDS
        #pragma unroll
        for (int n = 0; n < 4; ++n) {
            const f32x4 bias = *(const f32x4*)(biasS + key0 + n * 16 + quad * 4);
            f32x4 s_[4];
            #pragma unroll
            for (int mt = 0; mt < 4; ++mt) s_[mt] = bias;
            #pragma unroll
            for (int s = 0; s < 2; ++s)
                #pragma unroll
                for (int mt = 0; mt < 4; ++mt)
                    s_[mt] = __builtin_amdgcn_mfma_f32_16x16x32_bf16(kf[n * 2 + s], qa[mt][s], s_[mt], 0, 0, 0);
            #pragma unroll
            for (int mt = 0; mt < 4; ++mt) {
                bf16x4 p4;
                #pragma unroll
                for (int r = 0; r < 4; ++r) {
                    const float e = exp2f(s_[mt][r]);
                    lsum[mt] += e;
                    p4[r] = (__bf16)e;
                }
                *(bf16x4*)(P + (mt * 16 + l15) * PPAD + n * 16 + quad * 4) = p4;
            }
        }

        // prefetch NEXT tile's K fragments (consumed next iteration, after PV)
        const int keyn = ks * 256 + ((kt < 3) ? kt + 1 : 3) * 64;
        #pragma unroll
        for (int n = 0; n < 4; ++n)
            #pragma unroll
            for (int s = 0; s < 2; ++s)
                kf[n * 2 + s] = *(const bf16x8*)(kbase + (keyn + n * 16 + l15) * H_DIM + s * 32 + quad * 8);

        // re-read P as A-operand (per-wave buffer; DS in-order within wave -> no barrier)
        bf16x8 pa[4][2];
        #pragma unroll
        for (int mt = 0; mt < 4; ++mt)
            #pragma unroll
            for (int s = 0; s < 2; ++s)
                pa[mt][s] = *(const bf16x8*)(P + (mt * 16 + l15) * PPAD + s * 32 + quad * 8);

        // O' += P V, V fragment shared across 4 q-tiles
        #pragma unroll
        for (int t = 0; t < 4; ++t)
            #pragma unroll
            for (int s = 0; s < 2; ++s)
                #pragma unroll
                for (int mt = 0; mt < 4; ++mt)
                    oacc[mt][t] = __builtin_amdgcn_mfma_f32_16x16x32_bf16(pa[mt][s], vf[t * 2 + s], oacc[mt][t], 0, 0, 0);
    }

    #pragma unroll
    for (int mt = 0; mt < 4; ++mt) {
        lsum[mt] += __shfl_xor(lsum[mt], 16, 64);
        lsum[mt] += __shfl_xor(lsum[mt], 32, 64);
    }

    // ---- tree combine over 8 key-splits in LDS (reuses P region) ----
    float* cb = (float*)(arena + 8192);          // 4 x Ocomb[64][OPAD]
    float* Lc = cb + 4 * 64 * OPAD;              // [4][64]

    __syncthreads();
    // step 1: waves 4..7 write partials into buf[ks-4]
    if (ks >= 4) {
        float* bo = cb + (ks - 4) * (64 * OPAD);
        #pragma unroll
        for (int mt = 0; mt < 4; ++mt) {
            #pragma unroll
            for (int t = 0; t < 4; ++t)
                #pragma unroll
                for (int r = 0; r < 4; ++r)
                    bo[(mt * 16 + quad * 4 + r) * OPAD + t * 16 + l15] = oacc[mt][t][r];
            if (quad == 0) Lc[(ks - 4) * 64 + mt * 16 + l15] = lsum[mt];
        }
    }
    __syncthreads();
    // step 2: waves 0..3 add theirs -> 4 partial bufs {0+4, 1+5, 2+6, 3+7}
    if (ks < 4) {
        float* bo = cb + ks * (64 * OPAD);
        #pragma unroll
        for (int mt = 0; mt < 4; ++mt) {
            #pragma unroll
            for (int t = 0; t < 4; ++t)
                #pragma unroll
                for (int r = 0; r < 4; ++r)
                    bo[(mt * 16 + quad * 4 + r) * OPAD + t * 16 + l15] += oacc[mt][t][r];
            if (quad == 0) Lc[ks * 64 + mt * 16 + l15] += lsum[mt];
        }
    }
    __syncthreads();
    // step 3: 4 -> 2 (waves 0..3: buf0 += buf2; waves 4..7: buf1 += buf3), all waves busy
    {
        const int bsel = ks >> 2;
        float* dst = cb + bsel * (64 * OPAD);
        const float* src = cb + (bsel + 2) * (64 * OPAD);
        const int r0 = (ks & 3) * 16 + (lane >> 2);  // 16 rows per wave
        const int c0 = (lane & 3) * 16;
        #pragma unroll
        for (int k = 0; k < 4; ++k) {
            f32x4* d = (f32x4*)(dst + r0 * OPAD + c0 + k * 4);
            *d += *(const f32x4*)(src + r0 * OPAD + c0 + k * 4);
        }
        if (ks == 0) Lc[lane] += Lc[128 + lane];
        if (ks == 4) Lc[64 + lane] += Lc[192 + lane];
    }
    __syncthreads();
    // step 4: 2 -> 1, normalize, store. Wave ks owns rows ks*8 .. ks*8+7.
    {
        const int rr = lane >> 3;        // 0..7 row within wave's slab
        const int cc = lane & 7;         // 0..7 8-col chunk
        const int row = ks * 8 + rr;
        const int qpos = q0 + row;
        const float lv = Lc[row] + Lc[64 + row];
        const bool qvalid = biasS[qpos] == 0.f;  // query mask == key mask (pm[b][t])
        const float inv = (qvalid && lv > 0.f) ? 1.f / lv : 0.f;
        const float* b0 = cb + row * OPAD;
        const float* b1 = cb + 64 * OPAD + row * OPAD;
        #pragma unroll
        for (int k = 0; k < 2; ++k) {
            const int col = cc * 8 + k * 4;
            f32x4 o = *(const f32x4*)(b0 + col) + *(const f32x4*)(b1 + col);
            o *= inv;
            *(f32x4*)(out + (bT + qpos) * H_DIM + col) = o;
        }
    }
}

extern "C" void kernel_launch(void* const* d_in, const int* in_sizes, int n_in,
                              void* d_out, int out_size, void* d_ws, size_t ws_size,
                              hipStream_t stream) {
    const float* x  = (const float*)d_in[0];
    const int* pm   = (const int*)d_in[1];
    const float* Wk = (const float*)d_in[2];
    const float* Wq = (const float*)d_in[3];
    const float* Wv = (const float*)d_in[4];
    float* out = (float*)d_out;

    // ws: qb | kb | vT (bf16, 4MB each) | WtF (76.8KB)
    __bf16* qb  = (__bf16*)d_ws;
    __bf16* kb  = qb + QKV_ELEMS;
    __bf16* vT  = kb + QKV_ELEMS;
    __bf16* WtF = vT + QKV_ELEMS;

    prep_w<<<dim3((WTF_ELEMS + 255) / 256), dim3(256), 0, stream>>>(Wk, Wq, Wv, WtF);
    qkv_proj<<<dim3(BT_TOT / 64), dim3(256), 0, stream>>>(x, WtF, qb, kb, vT);
    attn<<<dim3(T_SEQ / 64, 16), dim3(512), 0, stream>>>(qb, kb, vT, pm, out);
}

// Round 2
// 148.553 us; speedup vs baseline: 1.9017x; 1.9017x over previous
//
#include <hip/hip_runtime.h>

// B=16, T=2048, C=200, H=64 attention head with padding mask.
// Round 8: fix round-7 spill catastrophe (launch_bounds(512,4) capped waves at 128 TOTAL
// regs on gfx950's unified VGPR/AGPR file; live set ~160 -> 513MB scratch writes, 202us).
// Occupancy lever retained but with a per-wave tile that FITS: 32 queries/block (2 q-tiles),
// grid 1024 blocks x 256 thr, launch_bounds(256,4). Demand ~110-120 total regs (oacc 32 AGPR,
// ~80 VGPR peak). SW K-prefetch dropped; V loads after QK -> TLP (4 waves/SIMD) hides latency.
// LDS 26.6KB (bias 8K + 4 waves x 32 x PPAD bf16 P, combine unioned). 4 blocks/CU exactly.

typedef __attribute__((ext_vector_type(8))) __bf16 bf16x8;
typedef __attribute__((ext_vector_type(4))) __bf16 bf16x4;
typedef __attribute__((ext_vector_type(4))) float f32x4;

#define T_SEQ 2048
#define C_DIM 200
#define H_DIM 64
#define BT_TOT 32768
#define QKV_ELEMS 2097152
#define PPAD 72            // P row pad (bf16): 2-way bank alias only
#define OPAD 68            // combine row pad (f32)
#define WTF_FULL 36864     // ks 0..5 full chunks: 6 * (3w*4t) * 512
#define WTF_ELEMS 38400    // + compact ks=6 chunk: 3*4*128 (c=192..199 only)
#define WTF_A_ELEMS 24576  // ks 0..3 (phase A, 48KB)
#define LOG2E 1.44269504088896f

// ---------------- Kernel 0: repack weights, compact MFMA fragment order ----------------
// Full chunk (ks<6, w, t): 512 bf16, elem lane*8+j = W_w[c=ks*32+(lane>>4)*8+j][h=t*16+(lane&15)]
// Compact ks=6 chunk (w, t): 128 bf16, elem l15*8+j = W_w[c=192+j][h=t*16+l15].
// w0 = Wq * (H^-0.5 * log2 e): scores land in log2 domain.
__global__ void prep_w(const float* __restrict__ Wk, const float* __restrict__ Wq,
                       const float* __restrict__ Wv, __bf16* __restrict__ WtF) {
    int idx = blockIdx.x * 256 + threadIdx.x;
    if (idx >= WTF_ELEMS) return;
    int w, c, h;
    if (idx < WTF_FULL) {
        int j = idx & 7, lane = (idx >> 3) & 63;
        int chunk = idx >> 9;                 // ks*12 + w*4 + t
        int t = chunk & 3, rest = chunk >> 2; // ks*3 + w
        w = rest % 3; int ks = rest / 3;
        c = ks * 32 + (lane >> 4) * 8 + j;
        h = t * 16 + (lane & 15);
    } else {
        int i2 = idx - WTF_FULL;
        int j = i2 & 7, l15 = (i2 >> 3) & 15, t = (i2 >> 7) & 3;
        w = i2 >> 9;
        c = 192 + j;
        h = t * 16 + l15;
    }
    const float* W = (w == 0) ? Wq : (w == 1) ? Wk : Wv;  // [C][H]
    float val = W[c * H_DIM + h];
    if (w == 0) val *= 0.125f * LOG2E;
    WtF[idx] = (__bf16)val;
}

// ---------------- Kernel 1: QKV projection ----------------
// grid = 512 blocks x 256 threads (4 waves x 16 rows = 64 rows/block), 2 waves/SIMD.
// W staged in LDS (two phases, 48KB); x direct-from-global A-fragments; vT via LDS transpose.
__global__ __launch_bounds__(256) void qkv_proj(const float* __restrict__ x,
                                                const __bf16* __restrict__ WtF,
                                                __bf16* __restrict__ qb,
                                                __bf16* __restrict__ kb,
                                                __bf16* __restrict__ vT) {
    __shared__ __bf16 Wl[WTF_A_ELEMS];  // 49152 B; reused phase B + transpose epilogue

    const int tid = threadIdx.x;
    const int wave = tid >> 6, lane = tid & 63, l15 = lane & 15, quad = lane >> 4;
    const int m0b = blockIdx.x * 64;
    const int row0 = m0b + wave * 16;

    f32x4 acc[3][4] = {};  // [w][h-tile], 16 rows per wave

    // ---- phase A: stage ks 0..3 (3072 x 16B over 256 threads = 12 iters), compute ----
    #pragma unroll
    for (int i = 0; i < 12; ++i) {
        const int c = i * 256 + tid;
        *(bf16x8*)(Wl + c * 8) = *(const bf16x8*)(WtF + c * 8);
    }
    __syncthreads();
    #pragma unroll
    for (int ks = 0; ks < 4; ++ks) {
        const float* xr = x + (size_t)(row0 + l15) * C_DIM + ks * 32 + quad * 8;
        const float4 f0 = *(const float4*)xr;
        const float4 f1 = *(const float4*)(xr + 4);
        bf16x8 a;
        a[0]=(__bf16)f0.x; a[1]=(__bf16)f0.y; a[2]=(__bf16)f0.z; a[3]=(__bf16)f0.w;
        a[4]=(__bf16)f1.x; a[5]=(__bf16)f1.y; a[6]=(__bf16)f1.z; a[7]=(__bf16)f1.w;
        #pragma unroll
        for (int w = 0; w < 3; ++w)
            #pragma unroll
            for (int t = 0; t < 4; ++t) {
                const bf16x8 bf = *(const bf16x8*)(Wl + ((ks * 12 + w * 4 + t) << 9) + lane * 8);
                acc[w][t] = __builtin_amdgcn_mfma_f32_16x16x32_bf16(a, bf, acc[w][t], 0, 0, 0);
            }
    }
    __syncthreads();

    // ---- phase B: stage ks 4..6 (1728 x 16B = 7 guarded iters), compute ----
    #pragma unroll
    for (int i = 0; i < 7; ++i) {
        const int c = i * 256 + tid;
        if (c < 1728)
            *(bf16x8*)(Wl + c * 8) = *(const bf16x8*)(WtF + WTF_A_ELEMS + c * 8);
    }
    __syncthreads();
    #pragma unroll
    for (int ks = 4; ks < 7; ++ks) {
        bf16x8 a;
        if (ks < 6 || quad == 0) {
            // ks=6,quad0 reads c 192..199 exactly (in-bounds); other quads are c>=200 -> A=0
            const float* xr = x + (size_t)(row0 + l15) * C_DIM + ks * 32 + quad * 8;
            const float4 f0 = *(const float4*)xr;
            const float4 f1 = *(const float4*)(xr + 4);
            a[0]=(__bf16)f0.x; a[1]=(__bf16)f0.y; a[2]=(__bf16)f0.z; a[3]=(__bf16)f0.w;
            a[4]=(__bf16)f1.x; a[5]=(__bf16)f1.y; a[6]=(__bf16)f1.z; a[7]=(__bf16)f1.w;
        } else {
            #pragma unroll
            for (int j = 0; j < 8; ++j) a[j] = (__bf16)0.f;
        }
        #pragma unroll
        for (int w = 0; w < 3; ++w)
            #pragma unroll
            for (int t = 0; t < 4; ++t) {
                // ks=6: compact chunk; quads 1..3 read quad0's data -> harmless (A rows are 0)
                const int off = (ks < 6) ? (((ks - 4) * 12 + w * 4 + t) << 9) + lane * 8
                                         : 12288 + ((w * 4 + t) << 7) + l15 * 8;
                const bf16x8 bf = *(const bf16x8*)(Wl + off);
                acc[w][t] = __builtin_amdgcn_mfma_f32_16x16x32_bf16(a, bf, acc[w][t], 0, 0, 0);
            }
    }

    // ---- epilogue: q,k direct stores; vT via LDS transpose for coalesced b128 ----
    #pragma unroll
    for (int t = 0; t < 4; ++t)
        #pragma unroll
        for (int r = 0; r < 4; ++r) {
            const size_t m = row0 + quad * 4 + r;
            qb[m * H_DIM + t * 16 + l15] = (__bf16)acc[0][t][r];
            kb[m * H_DIM + t * 16 + l15] = (__bf16)acc[1][t][r];
        }
    __syncthreads();
    #pragma unroll
    for (int t = 0; t < 4; ++t)
        #pragma unroll
        for (int r = 0; r < 4; ++r)
            Wl[(t * 16 + l15) * 72 + wave * 16 + quad * 4 + r] = (__bf16)acc[2][t][r];
    __syncthreads();
    const int bb = m0b >> 11, tloc = m0b & 2047;
    #pragma unroll
    for (int i = 0; i < 2; ++i) {
        const int seg = i * 256 + tid;          // 512 segs: h row, 8-elem column chunk
        const int h = seg >> 3, s8 = seg & 7;
        *(bf16x8*)(vT + ((size_t)bb * H_DIM + h) * T_SEQ + tloc + s8 * 8) =
            *(const bf16x8*)(Wl + h * 72 + s8 * 8);
    }
}

// ---------------- Kernel 2: attention, 32 queries/block, 4 key-splits ----------------
// grid = (T/32, B) = 1024 blocks; block = 256 (4 waves = 4 key-splits of 512).
// 4 blocks/CU x 4 waves = 4 waves/SIMD (TLP replaces round-6 SW pipeline).
// No-max softmax in log2 domain (S~N(0,1): exp safe in fp32; masked keys -> exact 0).
__global__ __launch_bounds__(256, 4) void attn(const __bf16* __restrict__ qb,
                                               const __bf16* __restrict__ kb,
                                               const __bf16* __restrict__ vT,
                                               const int* __restrict__ pm,
                                               float* __restrict__ out) {
    // arena: [0,8K) key bias f32[2048]; [8K,+18432) per-wave P (4 x 32 x PPAD bf16),
    // unioned with combine region Ocomb[32][OPAD] f32 + Lcomb[32] f32 (8832 B).
    __shared__ __align__(16) char arena[8192 + 4 * 32 * PPAD * 2];  // 26624 B
    float* biasS = (float*)arena;

    const int tid = threadIdx.x;
    const int wave = tid >> 6, lane = tid & 63, l15 = lane & 15, quad = lane >> 4;
    const int ks = wave;
    const int b = blockIdx.y;
    const int q0 = blockIdx.x * 32;
    const size_t bT = (size_t)b * T_SEQ;

    for (int i = tid; i < 512; i += 256) {
        const int4 p4 = *(const int4*)(pm + bT + i * 4);
        biasS[i * 4 + 0] = p4.x ? 0.f : -1e30f;
        biasS[i * 4 + 1] = p4.y ? 0.f : -1e30f;
        biasS[i * 4 + 2] = p4.z ? 0.f : -1e30f;
        biasS[i * 4 + 3] = p4.w ? 0.f : -1e30f;
    }
    __syncthreads();

    // Q fragments: qa[mt][s], lane holds Q[q0+mt*16+l15][s*32+quad*8 ..+8]
    bf16x8 qa[2][2];
    #pragma unroll
    for (int mt = 0; mt < 2; ++mt)
        #pragma unroll
        for (int s = 0; s < 2; ++s)
            qa[mt][s] = *(const bf16x8*)(qb + (bT + q0 + mt * 16 + l15) * H_DIM + s * 32 + quad * 8);

    __bf16* P = (__bf16*)(arena + 8192) + wave * (32 * PPAD);
    const __bf16* kbase = kb + bT * H_DIM;
    const __bf16* vbase = vT + (size_t)b * H_DIM * T_SEQ;

    f32x4 oacc[2][4] = {};              // O'[qtile][h-tile][row=quad*4+r]
    float lsum[2] = {0.f, 0.f};

    for (int kt = 0; kt < 8; ++kt) {
        const int key0 = ks * 512 + kt * 64;

        // K fragments for this tile: kf[n*2+s] = K[key0+n*16+l15][s*32+quad*8 ..+8]
        bf16x8 kf[8];
        #pragma unroll
        for (int n = 0; n < 4; ++n)
            #pragma unroll
            for (int s = 0; s < 2; ++s)
                kf[n * 2 + s] = *(const bf16x8*)(kbase + (key0 + n * 16 + l15) * H_DIM + s * 32 + quad * 8);

        // S'^T per n-block: 2 q-tiles share each K fragment; exp; P -> LDS
        #pragma unroll
        for (int n = 0; n < 4; ++n) {
            const f32x4 bias = *(const f32x4*)(biasS + key0 + n * 16 + quad * 4);
            f32x4 s_[2];
            #pragma unroll
            for (int mt = 0; mt < 2; ++mt) s_[mt] = bias;
            #pragma unroll
            for (int s = 0; s < 2; ++s)
                #pragma unroll
                for (int mt = 0; mt < 2; ++mt)
                    s_[mt] = __builtin_amdgcn_mfma_f32_16x16x32_bf16(kf[n * 2 + s], qa[mt][s], s_[mt], 0, 0, 0);
            #pragma unroll
            for (int mt = 0; mt < 2; ++mt) {
                bf16x4 p4;
                #pragma unroll
                for (int r = 0; r < 4; ++r) {
                    const float e = exp2f(s_[mt][r]);
                    lsum[mt] += e;
                    p4[r] = (__bf16)e;
                }
                *(bf16x4*)(P + (mt * 16 + l15) * PPAD + n * 16 + quad * 4) = p4;
            }
        }

        // V fragments (after QK: keeps peak VGPR below the 128-reg unified budget)
        bf16x8 vf[8];
        #pragma unroll
        for (int t = 0; t < 4; ++t)
            #pragma unroll
            for (int s = 0; s < 2; ++s)
                vf[t * 2 + s] = *(const bf16x8*)(vbase + (size_t)(t * 16 + l15) * T_SEQ + key0 + s * 32 + quad * 8);

        // re-read P as A-operand (per-wave buffer; DS in-order within wave -> no barrier)
        bf16x8 pa[2][2];
        #pragma unroll
        for (int mt = 0; mt < 2; ++mt)
            #pragma unroll
            for (int s = 0; s < 2; ++s)
                pa[mt][s] = *(const bf16x8*)(P + (mt * 16 + l15) * PPAD + s * 32 + quad * 8);

        // O' += P V, V fragment shared across 2 q-tiles
        #pragma unroll
        for (int t = 0; t < 4; ++t)
            #pragma unroll
            for (int s = 0; s < 2; ++s)
                #pragma unroll
                for (int mt = 0; mt < 2; ++mt)
                    oacc[mt][t] = __builtin_amdgcn_mfma_f32_16x16x32_bf16(pa[mt][s], vf[t * 2 + s], oacc[mt][t], 0, 0, 0);
    }

    #pragma unroll
    for (int mt = 0; mt < 2; ++mt) {
        lsum[mt] += __shfl_xor(lsum[mt], 16, 64);
        lsum[mt] += __shfl_xor(lsum[mt], 32, 64);
    }

    // in-LDS combine over the 4 key-splits (sequential; one 32-q tile per block)
    float* Ocomb = (float*)(arena + 8192);   // [32][OPAD]
    float* Lcomb = Ocomb + 32 * OPAD;        // [32]

    __syncthreads();
    if (ks == 1) {
        #pragma unroll
        for (int mt = 0; mt < 2; ++mt) {
            #pragma unroll
            for (int t = 0; t < 4; ++t)
                #pragma unroll
                for (int r = 0; r < 4; ++r)
                    Ocomb[(mt * 16 + quad * 4 + r) * OPAD + t * 16 + l15] = oacc[mt][t][r];
            if (quad == 0) Lcomb[mt * 16 + l15] = lsum[mt];
        }
    }
    __syncthreads();
    if (ks == 2) {
        #pragma unroll
        for (int mt = 0; mt < 2; ++mt) {
            #pragma unroll
            for (int t = 0; t < 4; ++t)
                #pragma unroll
                for (int r = 0; r < 4; ++r)
                    Ocomb[(mt * 16 + quad * 4 + r) * OPAD + t * 16 + l15] += oacc[mt][t][r];
            if (quad == 0) Lcomb[mt * 16 + l15] += lsum[mt];
        }
    }
    __syncthreads();
    if (ks == 3) {
        #pragma unroll
        for (int mt = 0; mt < 2; ++mt) {
            #pragma unroll
            for (int t = 0; t < 4; ++t)
                #pragma unroll
                for (int r = 0; r < 4; ++r)
                    Ocomb[(mt * 16 + quad * 4 + r) * OPAD + t * 16 + l15] += oacc[mt][t][r];
            if (quad == 0) Lcomb[mt * 16 + l15] += lsum[mt];
        }
    }
    __syncthreads();
    if (ks == 0) {
        #pragma unroll
        for (int mt = 0; mt < 2; ++mt) {
            lsum[mt] += Lcomb[mt * 16 + l15];
            #pragma unroll
            for (int t = 0; t < 4; ++t)
                #pragma unroll
                for (int r = 0; r < 4; ++r)
                    oacc[mt][t][r] += Ocomb[(mt * 16 + quad * 4 + r) * OPAD + t * 16 + l15];
            #pragma unroll
            for (int r = 0; r < 4; ++r) {
                const int qpos = q0 + mt * 16 + quad * 4 + r;
                const float lv = __shfl(lsum[mt], quad * 4 + r, 64);
                const bool qvalid = biasS[qpos] == 0.f;  // query mask == key mask (pm[b][t])
                const float inv = (qvalid && lv > 0.f) ? 1.f / lv : 0.f;
                #pragma unroll
                for (int t = 0; t < 4; ++t)
                    out[(bT + qpos) * H_DIM + t * 16 + l15] = oacc[mt][t][r] * inv;
            }
        }
    }
}

extern "C" void kernel_launch(void* const* d_in, const int* in_sizes, int n_in,
                              void* d_out, int out_size, void* d_ws, size_t ws_size,
                              hipStream_t stream) {
    const float* x  = (const float*)d_in[0];
    const int* pm   = (const int*)d_in[1];
    const float* Wk = (const float*)d_in[2];
    const float* Wq = (const float*)d_in[3];
    const float* Wv = (const float*)d_in[4];
    float* out = (float*)d_out;

    // ws: qb | kb | vT (bf16, 4MB each) | WtF (76.8KB)
    __bf16* qb  = (__bf16*)d_ws;
    __bf16* kb  = qb + QKV_ELEMS;
    __bf16* vT  = kb + QKV_ELEMS;
    __bf16* WtF = vT + QKV_ELEMS;

    prep_w<<<dim3((WTF_ELEMS + 255) / 256), dim3(256), 0, stream>>>(Wk, Wq, Wv, WtF);
    qkv_proj<<<dim3(BT_TOT / 64), dim3(256), 0, stream>>>(x, WtF, qb, kb, vT);
    attn<<<dim3(T_SEQ / 32, 16), dim3(256), 0, stream>>>(qb, kb, vT, pm, out);
}

// Round 3
// 125.914 us; speedup vs baseline: 2.2436x; 1.1798x over previous
//
#include <hip/hip_runtime.h>

// B=16, T=2048, C=200, H=64 attention head with padding mask.
// Round 9: revert to round-6 structure (fat 4-q-tile waves, 512-key splits, SW pipeline;
// 2 waves/SIMD is the REGISTER cap: 128 VGPR + 64 AGPR unified ~ 192/wave, so occupancy
// plays are dead — rounds 7/8 proved it). New: split the tile at s-granularity so the
// P LDS round-trip is pipelined: QK(n0,n1) -> issue pa[s=0] reads -> QK(n2,n3) hides the
// DS latency -> pa[s=1] reads -> K-prefetch (kf dead) -> PV(s0) -> PV(s1) -> V-prefetch
// (vf dead). Matrix pipe ping-pongs QK<->PV; both DS reads and both global prefetches
// land in covered windows.

typedef __attribute__((ext_vector_type(8))) __bf16 bf16x8;
typedef __attribute__((ext_vector_type(4))) __bf16 bf16x4;
typedef __attribute__((ext_vector_type(4))) float f32x4;

#define T_SEQ 2048
#define C_DIM 200
#define H_DIM 64
#define BT_TOT 32768
#define QKV_ELEMS 2097152
#define PPAD 72            // P row pad (bf16): 2-way bank alias only
#define OPAD 68            // combine row pad (f32)
#define WTF_FULL 36864     // ks 0..5 full chunks: 6 * (3w*4t) * 512
#define WTF_ELEMS 38400    // + compact ks=6 chunk: 3*4*128 (c=192..199 only)
#define WTF_A_ELEMS 24576  // ks 0..3 (phase A, 48KB)
#define LOG2E 1.44269504088896f

// ---------------- Kernel 0: repack weights, compact MFMA fragment order ----------------
// Full chunk (ks<6, w, t): 512 bf16, elem lane*8+j = W_w[c=ks*32+(lane>>4)*8+j][h=t*16+(lane&15)]
// Compact ks=6 chunk (w, t): 128 bf16, elem l15*8+j = W_w[c=192+j][h=t*16+l15].
// w0 = Wq * (H^-0.5 * log2 e): scores land in log2 domain.
__global__ void prep_w(const float* __restrict__ Wk, const float* __restrict__ Wq,
                       const float* __restrict__ Wv, __bf16* __restrict__ WtF) {
    int idx = blockIdx.x * 256 + threadIdx.x;
    if (idx >= WTF_ELEMS) return;
    int w, c, h;
    if (idx < WTF_FULL) {
        int j = idx & 7, lane = (idx >> 3) & 63;
        int chunk = idx >> 9;                 // ks*12 + w*4 + t
        int t = chunk & 3, rest = chunk >> 2; // ks*3 + w
        w = rest % 3; int ks = rest / 3;
        c = ks * 32 + (lane >> 4) * 8 + j;
        h = t * 16 + (lane & 15);
    } else {
        int i2 = idx - WTF_FULL;
        int j = i2 & 7, l15 = (i2 >> 3) & 15, t = (i2 >> 7) & 3;
        w = i2 >> 9;
        c = 192 + j;
        h = t * 16 + l15;
    }
    const float* W = (w == 0) ? Wq : (w == 1) ? Wk : Wv;  // [C][H]
    float val = W[c * H_DIM + h];
    if (w == 0) val *= 0.125f * LOG2E;
    WtF[idx] = (__bf16)val;
}

// ---------------- Kernel 1: QKV projection ----------------
// grid = 512 blocks x 256 threads (4 waves x 16 rows = 64 rows/block), 2 waves/SIMD.
// W staged in LDS (two phases, 48KB); x direct-from-global A-fragments; vT via LDS transpose.
__global__ __launch_bounds__(256) void qkv_proj(const float* __restrict__ x,
                                                const __bf16* __restrict__ WtF,
                                                __bf16* __restrict__ qb,
                                                __bf16* __restrict__ kb,
                                                __bf16* __restrict__ vT) {
    __shared__ __bf16 Wl[WTF_A_ELEMS];  // 49152 B; reused phase B + transpose epilogue

    const int tid = threadIdx.x;
    const int wave = tid >> 6, lane = tid & 63, l15 = lane & 15, quad = lane >> 4;
    const int m0b = blockIdx.x * 64;
    const int row0 = m0b + wave * 16;

    f32x4 acc[3][4] = {};  // [w][h-tile], 16 rows per wave

    // ---- phase A: stage ks 0..3 (3072 x 16B over 256 threads = 12 iters), compute ----
    #pragma unroll
    for (int i = 0; i < 12; ++i) {
        const int c = i * 256 + tid;
        *(bf16x8*)(Wl + c * 8) = *(const bf16x8*)(WtF + c * 8);
    }
    __syncthreads();
    #pragma unroll
    for (int ks = 0; ks < 4; ++ks) {
        const float* xr = x + (size_t)(row0 + l15) * C_DIM + ks * 32 + quad * 8;
        const float4 f0 = *(const float4*)xr;
        const float4 f1 = *(const float4*)(xr + 4);
        bf16x8 a;
        a[0]=(__bf16)f0.x; a[1]=(__bf16)f0.y; a[2]=(__bf16)f0.z; a[3]=(__bf16)f0.w;
        a[4]=(__bf16)f1.x; a[5]=(__bf16)f1.y; a[6]=(__bf16)f1.z; a[7]=(__bf16)f1.w;
        #pragma unroll
        for (int w = 0; w < 3; ++w)
            #pragma unroll
            for (int t = 0; t < 4; ++t) {
                const bf16x8 bf = *(const bf16x8*)(Wl + ((ks * 12 + w * 4 + t) << 9) + lane * 8);
                acc[w][t] = __builtin_amdgcn_mfma_f32_16x16x32_bf16(a, bf, acc[w][t], 0, 0, 0);
            }
    }
    __syncthreads();

    // ---- phase B: stage ks 4..6 (1728 x 16B = 7 guarded iters), compute ----
    #pragma unroll
    for (int i = 0; i < 7; ++i) {
        const int c = i * 256 + tid;
        if (c < 1728)
            *(bf16x8*)(Wl + c * 8) = *(const bf16x8*)(WtF + WTF_A_ELEMS + c * 8);
    }
    __syncthreads();
    #pragma unroll
    for (int ks = 4; ks < 7; ++ks) {
        bf16x8 a;
        if (ks < 6 || quad == 0) {
            // ks=6,quad0 reads c 192..199 exactly (in-bounds); other quads are c>=200 -> A=0
            const float* xr = x + (size_t)(row0 + l15) * C_DIM + ks * 32 + quad * 8;
            const float4 f0 = *(const float4*)xr;
            const float4 f1 = *(const float4*)(xr + 4);
            a[0]=(__bf16)f0.x; a[1]=(__bf16)f0.y; a[2]=(__bf16)f0.z; a[3]=(__bf16)f0.w;
            a[4]=(__bf16)f1.x; a[5]=(__bf16)f1.y; a[6]=(__bf16)f1.z; a[7]=(__bf16)f1.w;
        } else {
            #pragma unroll
            for (int j = 0; j < 8; ++j) a[j] = (__bf16)0.f;
        }
        #pragma unroll
        for (int w = 0; w < 3; ++w)
            #pragma unroll
            for (int t = 0; t < 4; ++t) {
                // ks=6: compact chunk; quads 1..3 read quad0's data -> harmless (A rows are 0)
                const int off = (ks < 6) ? (((ks - 4) * 12 + w * 4 + t) << 9) + lane * 8
                                         : 12288 + ((w * 4 + t) << 7) + l15 * 8;
                const bf16x8 bf = *(const bf16x8*)(Wl + off);
                acc[w][t] = __builtin_amdgcn_mfma_f32_16x16x32_bf16(a, bf, acc[w][t], 0, 0, 0);
            }
    }

    // ---- epilogue: q,k direct stores; vT via LDS transpose for coalesced b128 ----
    #pragma unroll
    for (int t = 0; t < 4; ++t)
        #pragma unroll
        for (int r = 0; r < 4; ++r) {
            const size_t m = row0 + quad * 4 + r;
            qb[m * H_DIM + t * 16 + l15] = (__bf16)acc[0][t][r];
            kb[m * H_DIM + t * 16 + l15] = (__bf16)acc[1][t][r];
        }
    __syncthreads();
    #pragma unroll
    for (int t = 0; t < 4; ++t)
        #pragma unroll
        for (int r = 0; r < 4; ++r)
            Wl[(t * 16 + l15) * 72 + wave * 16 + quad * 4 + r] = (__bf16)acc[2][t][r];
    __syncthreads();
    const int bb = m0b >> 11, tloc = m0b & 2047;
    #pragma unroll
    for (int i = 0; i < 2; ++i) {
        const int seg = i * 256 + tid;          // 512 segs: h row, 8-elem column chunk
        const int h = seg >> 3, s8 = seg & 7;
        *(bf16x8*)(vT + ((size_t)bb * H_DIM + h) * T_SEQ + tloc + s8 * 8) =
            *(const bf16x8*)(Wl + h * 72 + s8 * 8);
    }
}

// ---------------- Kernel 2: attention, 64 queries/wave, s-granular pipelined K-loop ----------------
// grid = (T/64, B); block = 256 (4 waves = 4 key-splits of 512, all same 64-q tile).
// No-max softmax in log2 domain (S~N(0,1): exp safe in fp32; masked keys -> exact 0).
__global__ __launch_bounds__(256, 2) void attn(const __bf16* __restrict__ qb,
                                               const __bf16* __restrict__ kb,
                                               const __bf16* __restrict__ vT,
                                               const int* __restrict__ pm,
                                               float* __restrict__ out) {
    // arena: [0,8K) key bias f32[2048]; [8K,+36864) per-wave P (4 x 64 x PPAD bf16),
    // unioned with combine region Ocomb[64][OPAD] f32 + Lcomb[64] f32.
    __shared__ __align__(16) char arena[8192 + 36864];
    float* biasS = (float*)arena;

    const int tid = threadIdx.x;
    const int wave = tid >> 6, lane = tid & 63, l15 = lane & 15, quad = lane >> 4;
    const int ks = wave;
    const int b = blockIdx.y;
    const int q0 = blockIdx.x * 64;
    const size_t bT = (size_t)b * T_SEQ;

    for (int i = tid; i < 512; i += 256) {
        const int4 p4 = *(const int4*)(pm + bT + i * 4);
        biasS[i * 4 + 0] = p4.x ? 0.f : -1e30f;
        biasS[i * 4 + 1] = p4.y ? 0.f : -1e30f;
        biasS[i * 4 + 2] = p4.z ? 0.f : -1e30f;
        biasS[i * 4 + 3] = p4.w ? 0.f : -1e30f;
    }
    __syncthreads();

    // Q fragments: qa[mt][s], lane holds Q[q0+mt*16+l15][s*32+quad*8 ..+8]
    bf16x8 qa[4][2];
    #pragma unroll
    for (int mt = 0; mt < 4; ++mt)
        #pragma unroll
        for (int s = 0; s < 2; ++s)
            qa[mt][s] = *(const bf16x8*)(qb + (bT + q0 + mt * 16 + l15) * H_DIM + s * 32 + quad * 8);

    __bf16* P = (__bf16*)(arena + 8192) + wave * (64 * PPAD);
    const __bf16* kbase = kb + bT * H_DIM;
    const __bf16* vbase = vT + (size_t)b * H_DIM * T_SEQ;

    f32x4 oacc[4][4] = {};              // O'[qtile][h-tile][row=quad*4+r]
    float lsum[4] = {0.f, 0.f, 0.f, 0.f};

    // preload K and V fragments for tile 0
    bf16x8 kf[8];   // kf[n*2+s] = K[key0+n*16+l15][s*32+quad*8 ..+8]
    bf16x8 vf[8];   // vf[t*2+s] = V^T[t*16+l15][key0+s*32+quad*8 ..+8]
    #pragma unroll
    for (int n = 0; n < 4; ++n)
        #pragma unroll
        for (int s = 0; s < 2; ++s)
            kf[n * 2 + s] = *(const bf16x8*)(kbase + (ks * 512 + n * 16 + l15) * H_DIM + s * 32 + quad * 8);
    #pragma unroll
    for (int t = 0; t < 4; ++t)
        #pragma unroll
        for (int s = 0; s < 2; ++s)
            vf[t * 2 + s] = *(const bf16x8*)(vbase + (size_t)(t * 16 + l15) * T_SEQ + ks * 512 + s * 32 + quad * 8);

    for (int kt = 0; kt < 8; ++kt) {
        const int key0 = ks * 512 + kt * 64;
        const int keyn = ks * 512 + ((kt < 7) ? kt + 1 : 7) * 64;  // clamped prefetch addr

        bf16x8 pa[4][2];

        // ---- QK half 1: n-blocks 0,1 -> exp -> P rows; then issue pa[s=0] reads ----
        #pragma unroll
        for (int n = 0; n < 2; ++n) {
            const f32x4 bias = *(const f32x4*)(biasS + key0 + n * 16 + quad * 4);
            f32x4 s_[4];
            #pragma unroll
            for (int mt = 0; mt < 4; ++mt) s_[mt] = bias;
            #pragma unroll
            for (int s = 0; s < 2; ++s)
                #pragma unroll
                for (int mt = 0; mt < 4; ++mt)
                    s_[mt] = __builtin_amdgcn_mfma_f32_16x16x32_bf16(kf[n * 2 + s], qa[mt][s], s_[mt], 0, 0, 0);
            #pragma unroll
            for (int mt = 0; mt < 4; ++mt) {
                bf16x4 p4;
                #pragma unroll
                for (int r = 0; r < 4; ++r) {
                    const float e = exp2f(s_[mt][r]);
                    lsum[mt] += e;
                    p4[r] = (__bf16)e;
                }
                *(bf16x4*)(P + (mt * 16 + l15) * PPAD + n * 16 + quad * 4) = p4;
            }
        }
        // pa[s=0] covers keys 0..31 = n-blocks 0,1 only; DS in-order within wave means
        // these reads wait only on the writes above, and their latency hides under QK n=2,3.
        #pragma unroll
        for (int mt = 0; mt < 4; ++mt)
            pa[mt][0] = *(const bf16x8*)(P + (mt * 16 + l15) * PPAD + quad * 8);

        // ---- QK half 2: n-blocks 2,3 -> exp -> P rows; then issue pa[s=1] reads ----
        #pragma unroll
        for (int n = 2; n < 4; ++n) {
            const f32x4 bias = *(const f32x4*)(biasS + key0 + n * 16 + quad * 4);
            f32x4 s_[4];
            #pragma unroll
            for (int mt = 0; mt < 4; ++mt) s_[mt] = bias;
            #pragma unroll
            for (int s = 0; s < 2; ++s)
                #pragma unroll
                for (int mt = 0; mt < 4; ++mt)
                    s_[mt] = __builtin_amdgcn_mfma_f32_16x16x32_bf16(kf[n * 2 + s], qa[mt][s], s_[mt], 0, 0, 0);
            #pragma unroll
            for (int mt = 0; mt < 4; ++mt) {
                bf16x4 p4;
                #pragma unroll
                for (int r = 0; r < 4; ++r) {
                    const float e = exp2f(s_[mt][r]);
                    lsum[mt] += e;
                    p4[r] = (__bf16)e;
                }
                *(bf16x4*)(P + (mt * 16 + l15) * PPAD + n * 16 + quad * 4) = p4;
            }
        }
        #pragma unroll
        for (int mt = 0; mt < 4; ++mt)
            pa[mt][1] = *(const bf16x8*)(P + (mt * 16 + l15) * PPAD + 32 + quad * 8);

        // ---- K prefetch for next tile (kf dead after QK half 2) ----
        #pragma unroll
        for (int n = 0; n < 4; ++n)
            #pragma unroll
            for (int s = 0; s < 2; ++s)
                kf[n * 2 + s] = *(const bf16x8*)(kbase + (keyn + n * 16 + l15) * H_DIM + s * 32 + quad * 8);

        // ---- PV s=0 (pa[s=1] DS latency hides under these 16 MFMAs) ----
        #pragma unroll
        for (int t = 0; t < 4; ++t)
            #pragma unroll
            for (int mt = 0; mt < 4; ++mt)
                oacc[mt][t] = __builtin_amdgcn_mfma_f32_16x16x32_bf16(pa[mt][0], vf[t * 2 + 0], oacc[mt][t], 0, 0, 0);

        // ---- PV s=1 ----
        #pragma unroll
        for (int t = 0; t < 4; ++t)
            #pragma unroll
            for (int mt = 0; mt < 4; ++mt)
                oacc[mt][t] = __builtin_amdgcn_mfma_f32_16x16x32_bf16(pa[mt][1], vf[t * 2 + 1], oacc[mt][t], 0, 0, 0);

        // ---- V prefetch for next tile (vf dead after PV s=1) ----
        if (kt < 7) {
            #pragma unroll
            for (int t = 0; t < 4; ++t)
                #pragma unroll
                for (int s = 0; s < 2; ++s)
                    vf[t * 2 + s] = *(const bf16x8*)(vbase + (size_t)(t * 16 + l15) * T_SEQ + keyn + s * 32 + quad * 8);
        }
    }

    #pragma unroll
    for (int mt = 0; mt < 4; ++mt) {
        lsum[mt] += __shfl_xor(lsum[mt], 16, 64);
        lsum[mt] += __shfl_xor(lsum[mt], 32, 64);
    }

    // in-LDS combine over the 4 key-splits (sequential; one 64-q tile per block)
    float* Ocomb = (float*)(arena + 8192);   // [64][OPAD]
    float* Lcomb = Ocomb + 64 * OPAD;        // [64]

    __syncthreads();
    if (ks == 1) {
        #pragma unroll
        for (int mt = 0; mt < 4; ++mt) {
            #pragma unroll
            for (int t = 0; t < 4; ++t)
                #pragma unroll
                for (int r = 0; r < 4; ++r)
                    Ocomb[(mt * 16 + quad * 4 + r) * OPAD + t * 16 + l15] = oacc[mt][t][r];
            if (quad == 0) Lcomb[mt * 16 + l15] = lsum[mt];
        }
    }
    __syncthreads();
    if (ks == 2) {
        #pragma unroll
        for (int mt = 0; mt < 4; ++mt) {
            #pragma unroll
            for (int t = 0; t < 4; ++t)
                #pragma unroll
                for (int r = 0; r < 4; ++r)
                    Ocomb[(mt * 16 + quad * 4 + r) * OPAD + t * 16 + l15] += oacc[mt][t][r];
            if (quad == 0) Lcomb[mt * 16 + l15] += lsum[mt];
        }
    }
    __syncthreads();
    if (ks == 3) {
        #pragma unroll
        for (int mt = 0; mt < 4; ++mt) {
            #pragma unroll
            for (int t = 0; t < 4; ++t)
                #pragma unroll
                for (int r = 0; r < 4; ++r)
                    Ocomb[(mt * 16 + quad * 4 + r) * OPAD + t * 16 + l15] += oacc[mt][t][r];
            if (quad == 0) Lcomb[mt * 16 + l15] += lsum[mt];
        }
    }
    __syncthreads();
    if (ks == 0) {
        #pragma unroll
        for (int mt = 0; mt < 4; ++mt) {
            lsum[mt] += Lcomb[mt * 16 + l15];
            #pragma unroll
            for (int t = 0; t < 4; ++t)
                #pragma unroll
                for (int r = 0; r < 4; ++r)
                    oacc[mt][t][r] += Ocomb[(mt * 16 + quad * 4 + r) * OPAD + t * 16 + l15];
            #pragma unroll
            for (int r = 0; r < 4; ++r) {
                const int qpos = q0 + mt * 16 + quad * 4 + r;
                const float lv = __shfl(lsum[mt], quad * 4 + r, 64);
                const bool qvalid = biasS[qpos] == 0.f;  // query mask == key mask (pm[b][t])
                const float inv = (qvalid && lv > 0.f) ? 1.f / lv : 0.f;
                #pragma unroll
                for (int t = 0; t < 4; ++t)
                    out[(bT + qpos) * H_DIM + t * 16 + l15] = oacc[mt][t][r] * inv;
            }
        }
    }
}

extern "C" void kernel_launch(void* const* d_in, const int* in_sizes, int n_in,
                              void* d_out, int out_size, void* d_ws, size_t ws_size,
                              hipStream_t stream) {
    const float* x  = (const float*)d_in[0];
    const int* pm   = (const int*)d_in[1];
    const float* Wk = (const float*)d_in[2];
    const float* Wq = (const float*)d_in[3];
    const float* Wv = (const float*)d_in[4];
    float* out = (float*)d_out;

    // ws: qb | kb | vT (bf16, 4MB each) | WtF (76.8KB)
    __bf16* qb  = (__bf16*)d_ws;
    __bf16* kb  = qb + QKV_ELEMS;
    __bf16* vT  = kb + QKV_ELEMS;
    __bf16* WtF = vT + QKV_ELEMS;

    prep_w<<<dim3((WTF_ELEMS + 255) / 256), dim3(256), 0, stream>>>(Wk, Wq, Wv, WtF);
    qkv_proj<<<dim3(BT_TOT / 64), dim3(256), 0, stream>>>(x, WtF, qb, kb, vT);
    attn<<<dim3(T_SEQ / 64, 16), dim3(256), 0, stream>>>(qb, kb, vT, pm, out);
}